// Round 1
// baseline (486.175 us; speedup 1.0000x reference)
//
#include <hip/hip_runtime.h>

#define HH 96
#define WW 192
#define PP (HH*WW)      // 18432 pixels per image
#define CC 256          // channels
#define NCODE 256       // codes
#define NIMG 8          // B*N = 4*2
#define PTILES (PP/64)  // 288

typedef unsigned short u16;
using short8 = __attribute__((ext_vector_type(8))) short;
using f32x4  = __attribute__((ext_vector_type(4))) float;

__device__ inline u16 f2bf(float f) {
    union { float f; unsigned u; } x; x.f = f;
    unsigned r = x.u + 0x7fffu + ((x.u >> 16) & 1u);   // RNE
    return (u16)(r >> 16);
}
__device__ inline float bf2f(u16 b) {
    union { unsigned u; float f; } x; x.u = ((unsigned)b) << 16;
    return x.f;
}

// ---------------- K0: norms, cosim mask, codebook fragment-order copies ----
// block n (256 blocks, 256 threads)
__global__ __launch_bounds__(256) void k_prep(const float* __restrict__ cb,
                                              const float* __restrict__ cbp,
                                              float* __restrict__ norms,
                                              int*   __restrict__ masked,
                                              u16*   __restrict__ cbF,
                                              u16*   __restrict__ cbTF) {
    __shared__ float cbn[256];
    __shared__ float red[256];
    int n = blockIdx.x, t = threadIdx.x;
    float v = cb[n*256 + t];
    cbn[t] = v;
    red[t] = v * v;
    __syncthreads();
    for (int s = 128; s > 0; s >>= 1) { if (t < s) red[t] += red[t+s]; __syncthreads(); }
    float norm2 = red[0];
    if (t == 0) norms[n] = norm2;
    __syncthreads();

    // cbF (GEMM1 B-operand frag order): cbF[((ks*16+nt)*64+l)*8+j] = cb[nt*16+(l&15)][ks*32+(l>>4)*8+j]
    {
        int ks = t >> 5, g = (t >> 3) & 3, j = t & 7;
        cbF[((size_t)(ks*16 + (n >> 4))*64 + g*16 + (n & 15))*8 + j] = f2bf(cbn[ks*32 + g*8 + j]);
    }
    // cbTF (GEMM2 A-operand frag order): cbTF[((ks*16+ct)*64+l)*8+j] = cb[ks*32+(l>>4)*8+j][ct*16+(l&15)]
    {
        int ct = t >> 4, cl = t & 15;
        int ks = n >> 5, g = (n >> 3) & 3, j = n & 7;
        cbTF[((size_t)(ks*16 + ct)*64 + g*16 + cl)*8 + j] = f2bf(cbn[ct*16 + cl]);
    }
    // cosim: thread m handles codebook_pub row m
    float dot = 0.f, np2 = 0.f;
    const float* pm = cbp + (size_t)t*256;
    for (int c = 0; c < 256; ++c) { float pv = pm[c]; dot += cbn[c]*pv; np2 += pv*pv; }
    float cosv = dot * rsqrtf(norm2 * np2);
    __syncthreads();
    red[t] = cosv;
    __syncthreads();
    for (int s = 128; s > 0; s >>= 1) { if (t < s) red[t] = fmaxf(red[t], red[t+s]); __syncthreads(); }
    if (t == 0) masked[n] = (red[0] <= 0.5f) ? 1 : 0;
}

// ---------------- K1: feature [img][c][p] f32 -> featT [img][p][c] bf16 ----
__global__ __launch_bounds__(256) void k_transpose(const float* __restrict__ feat,
                                                   u16* __restrict__ featT) {
    __shared__ float tile[64][65];
    int bid = blockIdx.x;
    int ct = bid & 3;
    int pt = (bid >> 2) % PTILES;
    int img = bid / (4*PTILES);
    int t = threadIdx.x;
    int c0 = ct*64, p0 = pt*64;
    const float* src = feat + (size_t)img*CC*PP + (size_t)c0*PP + p0;
    #pragma unroll
    for (int i = 0; i < 16; ++i) {
        int idx = t + i*256;
        int cc = idx >> 6, pp = idx & 63;
        tile[cc][pp] = src[(size_t)cc*PP + pp];
    }
    __syncthreads();
    int p = t >> 2, q = t & 3;
    short8 v0, v1;
    #pragma unroll
    for (int j = 0; j < 8; ++j) v0[j] = (short)f2bf(tile[q*16 + j][p]);
    #pragma unroll
    for (int j = 0; j < 8; ++j) v1[j] = (short)f2bf(tile[q*16 + 8 + j][p]);
    u16* dst = featT + ((size_t)img*PP + p0 + p)*256 + c0 + q*16;
    *(short8*)(dst)     = v0;
    *(short8*)(dst + 8) = v1;
}

// ---------------- K2: GEMM1 + sigmoid -> w_all [img][p][n] bf16 -----------
__global__ __launch_bounds__(256) void k_gemm1(const u16* __restrict__ featT,
                                               const u16* __restrict__ cbF,
                                               const float* __restrict__ norms,
                                               u16* __restrict__ w_all) {
    int bid = blockIdx.x;
    int img = bid / PTILES, pt = bid % PTILES;
    int t = threadIdx.x, wv = t >> 6, l = t & 63;
    int lr = l & 15, lg = l >> 4;
    int pw = pt*64 + wv*16;

    f32x4 acc[16];
    #pragma unroll
    for (int i = 0; i < 16; ++i) acc[i] = (f32x4){0.f,0.f,0.f,0.f};

    const u16* aptr = featT + ((size_t)img*PP + pw + lr)*256 + lg*8;
    const u16* bptr = cbF + (size_t)l*8;
    #pragma unroll
    for (int ks = 0; ks < 8; ++ks) {
        short8 a = *(const short8*)(aptr + ks*32);
        #pragma unroll
        for (int nt = 0; nt < 16; ++nt) {
            short8 b = *(const short8*)(bptr + (size_t)(ks*16 + nt)*512);
            acc[nt] = __builtin_amdgcn_mfma_f32_16x16x32_bf16(a, b, acc[nt], 0, 0, 0);
        }
    }
    #pragma unroll
    for (int nt = 0; nt < 16; ++nt) {
        int n = nt*16 + lr;
        float nrm = norms[n];
        #pragma unroll
        for (int r = 0; r < 4; ++r) {
            int p = pw + lg*4 + r;
            float x = acc[nt][r] / nrm;
            float wgt = 1.f / (1.f + __expf(-x));
            w_all[((size_t)img*PP + p)*256 + n] = f2bf(wgt);
        }
    }
}

// ---------------- K3: select/warp + softmax + GEMM2 -> out ----------------
__global__ __launch_bounds__(256) void k_out(const u16* __restrict__ w_all,
                                             const u16* __restrict__ cbTF,
                                             const int* __restrict__ masked,
                                             const float* __restrict__ am,
                                             float* __restrict__ out) {
    __shared__ alignas(16) u16 smx[64*264];   // [64 p][264 n] bf16, padded rows
    int bid = blockIdx.x;
    int img = bid / PTILES, pt = bid % PTILES;
    int t = threadIdx.x;

    // ---- phase A: build softmax'd weights tile in LDS ----
    {
        int pl = t >> 2, q = t & 3;            // pixel-local, n-quarter
        int p = pt*64 + pl;
        float vals[64];
        const u16* own = w_all + ((size_t)img*PP + p)*256 + q*64;
        #pragma unroll
        for (int i = 0; i < 8; ++i) {
            short8 v = *(const short8*)(own + i*8);
            #pragma unroll
            for (int j = 0; j < 8; ++j) vals[i*8 + j] = bf2f((u16)v[j]);
        }
        if (img & 1) {   // agent-1 image: masked codes get warped agent-0 weights
            int hh = p / WW, ww = p % WW;
            const float* th = am + (size_t)img*12;    // affine_matrix[bb][i][0]
            float gx = ww * (2.f/(WW-1)) - 1.f;
            float gy = hh * (2.f/(HH-1)) - 1.f;
            float xr = th[0]*gx + th[1]*gy + th[2];
            float yr = th[3]*gx + th[4]*gy + th[5];
            float x = (xr + 1.f) * ((WW-1)*0.5f);
            float y = (yr + 1.f) * ((HH-1)*0.5f);
            float x0f = floorf(x), y0f = floorf(y);
            float dx = x - x0f, dy = y - y0f;
            int x0 = (int)x0f, y0 = (int)y0f;
            float wc4[4] = {(1.f-dx)*(1.f-dy), dx*(1.f-dy), (1.f-dx)*dy, dx*dy};
            int xs_[4] = {x0, x0+1, x0, x0+1};
            int ys_[4] = {y0, y0, y0+1, y0+1};
            const u16* w0 = w_all + ((size_t)(img-1)*PP)*256;
            const u16* cptr[4];
            #pragma unroll
            for (int k = 0; k < 4; ++k) {
                bool ok = (xs_[k] >= 0) & (xs_[k] < WW) & (ys_[k] >= 0) & (ys_[k] < HH);
                cptr[k] = ok ? (w0 + ((size_t)(ys_[k]*WW + xs_[k]))*256 + q*64) : nullptr;
            }
            #pragma unroll
            for (int ch = 0; ch < 4; ++ch) {     // 4 chunks of 16 codes: cap registers
                float wch[16];
                #pragma unroll
                for (int i = 0; i < 16; ++i) wch[i] = 0.f;
                #pragma unroll
                for (int k = 0; k < 4; ++k) {
                    if (cptr[k]) {
                        const u16* cp = cptr[k] + ch*16;
                        short8 a = *(const short8*)(cp);
                        short8 b = *(const short8*)(cp + 8);
                        float wk = wc4[k];
                        #pragma unroll
                        for (int j = 0; j < 8; ++j) { wch[j] += wk*bf2f((u16)a[j]); wch[8+j] += wk*bf2f((u16)b[j]); }
                    }
                }
                #pragma unroll
                for (int i = 0; i < 16; ++i)
                    if (masked[q*64 + ch*16 + i]) vals[ch*16 + i] = wch[i];
            }
        }
        // softmax over 256 codes = 4 threads (consecutive lanes) x 64 values
        float m = vals[0];
        #pragma unroll
        for (int i = 1; i < 64; ++i) m = fmaxf(m, vals[i]);
        m = fmaxf(m, __shfl_xor(m, 1));
        m = fmaxf(m, __shfl_xor(m, 2));
        float s = 0.f;
        #pragma unroll
        for (int i = 0; i < 64; ++i) { vals[i] = __expf(vals[i] - m); s += vals[i]; }
        s += __shfl_xor(s, 1);
        s += __shfl_xor(s, 2);
        float inv = 1.f / s;
        u16* row = smx + pl*264 + q*64;
        #pragma unroll
        for (int i = 0; i < 8; ++i) {
            short8 v;
            #pragma unroll
            for (int j = 0; j < 8; ++j) v[j] = (short)f2bf(vals[i*8 + j] * inv);
            *(short8*)(row + i*8) = v;
        }
    }
    __syncthreads();

    // ---- phase B: GEMM2  out[c][p] = sum_n cbT[c][n] * smx[p][n] ----
    int wv = t >> 6, l = t & 63;
    int lr = l & 15, lg = l >> 4;
    int cw = wv * 64;
    f32x4 acc[4][4];
    #pragma unroll
    for (int i = 0; i < 4; ++i)
        #pragma unroll
        for (int j = 0; j < 4; ++j) acc[i][j] = (f32x4){0.f,0.f,0.f,0.f};

    const u16* abase = cbTF + (size_t)l*8;
    #pragma unroll
    for (int ks = 0; ks < 8; ++ks) {
        short8 a[4], b[4];
        #pragma unroll
        for (int ct = 0; ct < 4; ++ct)
            a[ct] = *(const short8*)(abase + (size_t)(ks*16 + cw/16 + ct)*512);
        #pragma unroll
        for (int p4 = 0; p4 < 4; ++p4)
            b[p4] = *(const short8*)(smx + (p4*16 + lr)*264 + ks*32 + lg*8);
        #pragma unroll
        for (int ct = 0; ct < 4; ++ct)
            #pragma unroll
            for (int p4 = 0; p4 < 4; ++p4)
                acc[ct][p4] = __builtin_amdgcn_mfma_f32_16x16x32_bf16(a[ct], b[p4], acc[ct][p4], 0, 0, 0);
    }
    #pragma unroll
    for (int ct = 0; ct < 4; ++ct)
        #pragma unroll
        for (int p4 = 0; p4 < 4; ++p4)
            #pragma unroll
            for (int r = 0; r < 4; ++r) {
                int cgl = cw + ct*16 + lg*4 + r;
                int pgl = pt*64 + p4*16 + lr;
                out[((size_t)img*CC + cgl)*PP + pgl] = acc[ct][p4][r];
            }
}

extern "C" void kernel_launch(void* const* d_in, const int* in_sizes, int n_in,
                              void* d_out, int out_size, void* d_ws, size_t ws_size,
                              hipStream_t stream) {
    const float* feature = (const float*)d_in[0];
    const float* cb      = (const float*)d_in[1];
    const float* cbp     = (const float*)d_in[2];
    const float* am      = (const float*)d_in[3];
    // d_in[4] = record_len: uniform N=2 (static in reference), unused
    float* out = (float*)d_out;

    char* ws = (char*)d_ws;
    size_t o = 0;
    u16* featT = (u16*)(ws + o); o += (size_t)NIMG*PP*CC*2;    // 75.5 MB
    u16* w_all = (u16*)(ws + o); o += (size_t)NIMG*PP*NCODE*2; // 75.5 MB
    u16* cbF   = (u16*)(ws + o); o += 256*256*2;
    u16* cbTF  = (u16*)(ws + o); o += 256*256*2;
    float* norms = (float*)(ws + o); o += 256*4;
    int* masked  = (int*)(ws + o);   o += 256*4;

    hipLaunchKernelGGL(k_prep, dim3(256), dim3(256), 0, stream, cb, cbp, norms, masked, cbF, cbTF);
    hipLaunchKernelGGL(k_transpose, dim3(NIMG*PTILES*4), dim3(256), 0, stream, feature, featT);
    hipLaunchKernelGGL(k_gemm1, dim3(NIMG*PTILES), dim3(256), 0, stream, featT, cbF, norms, w_all);
    hipLaunchKernelGGL(k_out, dim3(NIMG*PTILES), dim3(256), 0, stream, w_all, cbTF, masked, am, out);
}

// Round 2
// 351.513 us; speedup vs baseline: 1.3831x; 1.3831x over previous
//
#include <hip/hip_runtime.h>

#define HH 96
#define WW 192
#define PP (HH*WW)      // 18432 pixels per image
#define CC 256          // channels
#define NCODE 256       // codes
#define NIMG 8          // B*N = 4*2
#define PT 64           // pixel tile per block
#define PTILES (PP/PT)  // 288

typedef unsigned short u16;
typedef unsigned int u32;
using short8 = __attribute__((ext_vector_type(8))) short;
using f32x4  = __attribute__((ext_vector_type(4))) float;

__device__ inline u16 f2bf(float f) {
    union { float f; u32 u; } x; x.f = f;
    u32 r = x.u + 0x7fffu + ((x.u >> 16) & 1u);   // RNE
    return (u16)(r >> 16);
}
__device__ inline float bf2f(u16 b) {
    union { u32 u; float f; } x; x.u = ((u32)b) << 16;
    return x.f;
}

// ---------------- K0: inv-norms, cosim mask, codebook fragment-order copies
__global__ __launch_bounds__(256) void k_prep(const float* __restrict__ cb,
                                              const float* __restrict__ cbp,
                                              float* __restrict__ invnorms,
                                              int*   __restrict__ masked,
                                              u16*   __restrict__ cbF,
                                              u16*   __restrict__ cbTF) {
    __shared__ float cbn[256];
    __shared__ float red[256];
    int n = blockIdx.x, t = threadIdx.x;
    float v = cb[n*256 + t];
    cbn[t] = v;
    red[t] = v * v;
    __syncthreads();
    for (int s = 128; s > 0; s >>= 1) { if (t < s) red[t] += red[t+s]; __syncthreads(); }
    float norm2 = red[0];
    if (t == 0) invnorms[n] = 1.0f / norm2;
    __syncthreads();

    // cbF (GEMM1 B-operand frag order): frag(ks,nt): lane l, elem j = cb[nt*16+(l&15)][ks*32+(l>>4)*8+j]
    {
        int ks = t >> 5, g = (t >> 3) & 3, j = t & 7;
        cbF[((size_t)(ks*16 + (n >> 4))*64 + g*16 + (n & 15))*8 + j] = f2bf(cbn[ks*32 + g*8 + j]);
    }
    // cbTF (GEMM2 A-operand frag order): frag(ks,ct): lane l, elem j = cbT[ct*16+(l&15)][ks*32+(l>>4)*8+j]
    {
        int ct = t >> 4, cl = t & 15;
        int ks = n >> 5, g = (n >> 3) & 3, j = n & 7;
        cbTF[((size_t)(ks*16 + ct)*64 + g*16 + cl)*8 + j] = f2bf(cbn[ct*16 + cl]);
    }
    // cosim: thread m handles codebook_pub row m (vectorized)
    float dot = 0.f, np2 = 0.f;
    const float4* pm4 = (const float4*)(cbp + (size_t)t*256);
    for (int c4 = 0; c4 < 64; ++c4) {
        float4 pv = pm4[c4];
        dot += cbn[c4*4+0]*pv.x + cbn[c4*4+1]*pv.y + cbn[c4*4+2]*pv.z + cbn[c4*4+3]*pv.w;
        np2 += pv.x*pv.x + pv.y*pv.y + pv.z*pv.z + pv.w*pv.w;
    }
    float cosv = dot * rsqrtf(norm2 * np2);
    __syncthreads();
    red[t] = cosv;
    __syncthreads();
    for (int s = 128; s > 0; s >>= 1) { if (t < s) red[t] = fmaxf(red[t], red[t+s]); __syncthreads(); }
    if (t == 0) masked[n] = (red[0] <= 0.5f) ? 1 : 0;
}

// ---------------- K1: fused transpose + GEMM1 + sigmoid -> w_all [img][p][n]
// Block: 64 px tile, 256 threads (4 waves). Wave wv owns codes [wv*64, wv*64+64).
// A (feature tile) staged in LDS in MFMA-fragment order; B (codebook) in registers.
__global__ __launch_bounds__(256, 2) void k_gemm1f(const float* __restrict__ feat,
                                                   const u16* __restrict__ cbF,
                                                   const float* __restrict__ invnorms,
                                                   u16* __restrict__ w_all) {
    __shared__ alignas(16) u16 alds[32*64*8];   // 32 frags (m*8+ks) x 64 lanes x 8 = 32 KB
    int bid = blockIdx.x;
    int img = bid / PTILES, pt = bid % PTILES;
    int p0 = pt * PT;
    int t = threadIdx.x, wv = t >> 6, l = t & 63;
    int lr = l & 15, lg = l >> 4;

    // B fragments in registers: 32 x short8 = 128 VGPR, loaded once
    short8 breg[32];
    #pragma unroll
    for (int nt = 0; nt < 4; ++nt)
        #pragma unroll
        for (int ks = 0; ks < 8; ++ks)
            breg[nt*8 + ks] = *(const short8*)(cbF + ((size_t)((ks*16 + wv*4 + nt)*64 + l))*8);

    float invn[4];
    #pragma unroll
    for (int nt = 0; nt < 4; ++nt) invn[nt] = invnorms[wv*64 + nt*16 + lr];

    // ---- stage A: feature[c][p] f32 -> bf16 fragment-order LDS ----
    // thread t: pixel px = t&63 (coalesced global), channel group cgrp = t>>6
    int px = t & 63;
    int cgrp = t >> 6;
    const float* fb = feat + ((size_t)img*CC)*PP + p0 + px;
    int m_ = px >> 4;
    int lslot = px & 15;
    #pragma unroll
    for (int i = 0; i < 16; ++i) {
        int c0 = i*16 + cgrp*4;                 // 4 consecutive channels
        float f0 = fb[(size_t)(c0+0)*PP];
        float f1 = fb[(size_t)(c0+1)*PP];
        float f2 = fb[(size_t)(c0+2)*PP];
        float f3 = fb[(size_t)(c0+3)*PP];
        u32 lo = (u32)f2bf(f0) | ((u32)f2bf(f1) << 16);
        u32 hi = (u32)f2bf(f2) | ((u32)f2bf(f3) << 16);
        int ks = c0 >> 5;
        int lane = lslot + (((c0 >> 3) & 3) << 4);
        u32* dst = (u32*)((char*)alds + ((size_t)((m_*8 + ks)*64 + lane))*16 + (c0 & 7)*2);
        dst[0] = lo; dst[1] = hi;
    }
    __syncthreads();

    // ---- MFMA: per wave 4 m-frags x 8 ks x 4 nt = 128 MFMAs ----
    #pragma unroll
    for (int m = 0; m < 4; ++m) {
        f32x4 acc[4];
        #pragma unroll
        for (int nt = 0; nt < 4; ++nt) acc[nt] = (f32x4){0.f,0.f,0.f,0.f};
        #pragma unroll
        for (int ks = 0; ks < 8; ++ks) {
            short8 a = *(const short8*)(alds + ((size_t)((m*8 + ks)*64 + l))*8);
            #pragma unroll
            for (int nt = 0; nt < 4; ++nt)
                acc[nt] = __builtin_amdgcn_mfma_f32_16x16x32_bf16(a, breg[nt*8 + ks], acc[nt], 0, 0, 0);
        }
        // epilogue: sigmoid(acc/norm) -> bf16 store
        #pragma unroll
        for (int nt = 0; nt < 4; ++nt) {
            #pragma unroll
            for (int r = 0; r < 4; ++r) {
                int p = p0 + m*16 + lg*4 + r;
                int n = wv*64 + nt*16 + lr;
                float x = acc[nt][r] * invn[nt];
                float w = 1.f / (1.f + __expf(-x));
                w_all[((size_t)img*PP + p)*256 + n] = f2bf(w);
            }
        }
    }
}

// ---------------- K2: select/warp + softmax + GEMM2 -> out ----------------
// Wave wv owns channels [wv*64, wv*64+64); A (cbTF) in registers, B (smx) in
// fragment-order LDS (conflict-free ds_read_b128).
__global__ __launch_bounds__(256, 2) void k_out(const u16* __restrict__ w_all,
                                                const u16* __restrict__ cbTF,
                                                const int* __restrict__ masked,
                                                const float* __restrict__ am,
                                                float* __restrict__ out) {
    __shared__ alignas(16) u16 smx[32*64*8];   // 32 frags (ks*4+p4) x 64 lanes x 8 = 32 KB
    int bid = blockIdx.x;
    int img = bid / PTILES, pt = bid % PTILES;
    int p0 = pt * PT;
    int t = threadIdx.x;

    // ---- phase A: build softmax'd weights tile in LDS (frag order) ----
    {
        int pl = t >> 2, q = t & 3;            // pixel-local, n-quarter
        int p = p0 + pl;
        float vals[64];
        const u16* own = w_all + ((size_t)img*PP + p)*256 + q*64;
        #pragma unroll
        for (int i = 0; i < 8; ++i) {
            short8 v = *(const short8*)(own + i*8);
            #pragma unroll
            for (int j = 0; j < 8; ++j) vals[i*8 + j] = bf2f((u16)v[j]);
        }
        if (img & 1) {   // agent-1 image: masked codes get warped agent-0 weights
            int hh = p / WW, ww = p % WW;
            const float* th = am + (size_t)img*12;    // affine_matrix[bb][i][0]
            float gx = ww * (2.f/(WW-1)) - 1.f;
            float gy = hh * (2.f/(HH-1)) - 1.f;
            float xr = th[0]*gx + th[1]*gy + th[2];
            float yr = th[3]*gx + th[4]*gy + th[5];
            float x = (xr + 1.f) * ((WW-1)*0.5f);
            float y = (yr + 1.f) * ((HH-1)*0.5f);
            float x0f = floorf(x), y0f = floorf(y);
            float dx = x - x0f, dy = y - y0f;
            int x0 = (int)x0f, y0 = (int)y0f;
            float wc4[4] = {(1.f-dx)*(1.f-dy), dx*(1.f-dy), (1.f-dx)*dy, dx*dy};
            int xs_[4] = {x0, x0+1, x0, x0+1};
            int ys_[4] = {y0, y0, y0+1, y0+1};
            const u16* w0 = w_all + ((size_t)(img-1)*PP)*256;
            const u16* cptr[4];
            #pragma unroll
            for (int k = 0; k < 4; ++k) {
                bool ok = (xs_[k] >= 0) & (xs_[k] < WW) & (ys_[k] >= 0) & (ys_[k] < HH);
                cptr[k] = ok ? (w0 + ((size_t)(ys_[k]*WW + xs_[k]))*256 + q*64) : nullptr;
            }
            #pragma unroll
            for (int ch = 0; ch < 4; ++ch) {     // 4 chunks of 16 codes
                float wch[16];
                #pragma unroll
                for (int i = 0; i < 16; ++i) wch[i] = 0.f;
                #pragma unroll
                for (int k = 0; k < 4; ++k) {
                    if (cptr[k]) {
                        const u16* cp = cptr[k] + ch*16;
                        short8 a = *(const short8*)(cp);
                        short8 b = *(const short8*)(cp + 8);
                        float wk = wc4[k];
                        #pragma unroll
                        for (int j = 0; j < 8; ++j) { wch[j] += wk*bf2f((u16)a[j]); wch[8+j] += wk*bf2f((u16)b[j]); }
                    }
                }
                #pragma unroll
                for (int i = 0; i < 16; ++i)
                    if (masked[q*64 + ch*16 + i]) vals[ch*16 + i] = wch[i];
            }
        }
        // softmax over 256 codes = 4 lanes x 64 values
        float m = vals[0];
        #pragma unroll
        for (int i = 1; i < 64; ++i) m = fmaxf(m, vals[i]);
        m = fmaxf(m, __shfl_xor(m, 1));
        m = fmaxf(m, __shfl_xor(m, 2));
        float s = 0.f;
        #pragma unroll
        for (int i = 0; i < 64; ++i) { vals[i] = __expf(vals[i] - m); s += vals[i]; }
        s += __shfl_xor(s, 1);
        s += __shfl_xor(s, 2);
        float inv = 1.f / s;
        // write frag-order: frag(ks,p4): lane lane_, elem j = smx[n = ks*32+(lane>>4)*8+j][p = p4*16+(lane&15)]
        int p4 = pl >> 4;
        #pragma unroll
        for (int i = 0; i < 32; ++i) {
            int n = q*64 + i*2;
            int ks = n >> 5;
            int lane = (pl & 15) + (((n >> 3) & 3) << 4);
            u32 v = (u32)f2bf(vals[i*2] * inv) | ((u32)f2bf(vals[i*2+1] * inv) << 16);
            *(u32*)((char*)smx + ((size_t)((ks*4 + p4)*64 + lane))*16 + (n & 7)*2) = v;
        }
    }

    // A (cbTF) fragments into registers (after phase A to limit pressure overlap)
    int wv = t >> 6, l = t & 63;
    int lr = l & 15, lg = l >> 4;
    short8 areg[32];
    #pragma unroll
    for (int ct = 0; ct < 4; ++ct)
        #pragma unroll
        for (int ks = 0; ks < 8; ++ks)
            areg[ct*8 + ks] = *(const short8*)(cbTF + ((size_t)((ks*16 + wv*4 + ct)*64 + l))*8);
    __syncthreads();

    // ---- phase B: GEMM2  out[c][p] = sum_n cbT[c][n] * smx_frag ----
    f32x4 acc[4][4];
    #pragma unroll
    for (int i = 0; i < 4; ++i)
        #pragma unroll
        for (int j = 0; j < 4; ++j) acc[i][j] = (f32x4){0.f,0.f,0.f,0.f};

    #pragma unroll
    for (int ks = 0; ks < 8; ++ks) {
        short8 b[4];
        #pragma unroll
        for (int p4 = 0; p4 < 4; ++p4)
            b[p4] = *(const short8*)(smx + ((size_t)((ks*4 + p4)*64 + l))*8);
        #pragma unroll
        for (int ct = 0; ct < 4; ++ct)
            #pragma unroll
            for (int p4 = 0; p4 < 4; ++p4)
                acc[ct][p4] = __builtin_amdgcn_mfma_f32_16x16x32_bf16(areg[ct*8 + ks], b[p4], acc[ct][p4], 0, 0, 0);
    }
    #pragma unroll
    for (int ct = 0; ct < 4; ++ct)
        #pragma unroll
        for (int p4 = 0; p4 < 4; ++p4)
            #pragma unroll
            for (int r = 0; r < 4; ++r) {
                int c = wv*64 + ct*16 + lg*4 + r;
                int p = p0 + p4*16 + lr;
                out[((size_t)img*CC + c)*PP + p] = acc[ct][p4][r];
            }
}

extern "C" void kernel_launch(void* const* d_in, const int* in_sizes, int n_in,
                              void* d_out, int out_size, void* d_ws, size_t ws_size,
                              hipStream_t stream) {
    const float* feature = (const float*)d_in[0];
    const float* cb      = (const float*)d_in[1];
    const float* cbp     = (const float*)d_in[2];
    const float* am      = (const float*)d_in[3];
    float* out = (float*)d_out;

    char* ws = (char*)d_ws;
    size_t o = 0;
    u16* w_all = (u16*)(ws + o); o += (size_t)NIMG*PP*NCODE*2; // 75.5 MB
    u16* cbF   = (u16*)(ws + o); o += 256*256*2;
    u16* cbTF  = (u16*)(ws + o); o += 256*256*2;
    float* invnorms = (float*)(ws + o); o += 256*4;
    int* masked     = (int*)(ws + o);   o += 256*4;

    hipLaunchKernelGGL(k_prep, dim3(256), dim3(256), 0, stream, cb, cbp, invnorms, masked, cbF, cbTF);
    hipLaunchKernelGGL(k_gemm1f, dim3(NIMG*PTILES), dim3(256), 0, stream, feature, cbF, invnorms, w_all);
    hipLaunchKernelGGL(k_out, dim3(NIMG*PTILES), dim3(256), 0, stream, w_all, cbTF, masked, am, out);
}

// Round 3
// 332.616 us; speedup vs baseline: 1.4617x; 1.0568x over previous
//
#include <hip/hip_runtime.h>

#define HH 96
#define WW 192
#define PP (HH*WW)      // 18432 pixels per image
#define CC 256          // channels
#define NCODE 256       // codes
#define NIMG 8          // B*N = 4*2
#define PT 64           // pixel tile per block
#define PTILES (PP/PT)  // 288

typedef unsigned short u16;
typedef unsigned int u32;
using short8 = __attribute__((ext_vector_type(8))) short;
using f32x4  = __attribute__((ext_vector_type(4))) float;

__device__ inline u16 f2bf(float f) {
    union { float f; u32 u; } x; x.f = f;
    u32 r = x.u + 0x7fffu + ((x.u >> 16) & 1u);   // RNE
    return (u16)(r >> 16);
}
__device__ inline float bf2f(u16 b) {
    union { u32 u; float f; } x; x.u = ((u32)b) << 16;
    return x.f;
}

// meta layout: meta[0] = unmasked_cnt, meta[1..8] = 256-bit mask words
// ---------------- K0: inv-norms, cosim mask, codebook fragment-order copies
__global__ __launch_bounds__(256) void k_prep(const float* __restrict__ cb,
                                              const float* __restrict__ cbp,
                                              float* __restrict__ invnorms,
                                              int*   __restrict__ meta,
                                              u16*   __restrict__ cbF,
                                              u16*   __restrict__ cbTF) {
    __shared__ float cbn[256];
    __shared__ float red[256];
    int n = blockIdx.x, t = threadIdx.x;
    float v = cb[n*256 + t];
    cbn[t] = v;
    red[t] = v * v;
    __syncthreads();
    for (int s = 128; s > 0; s >>= 1) { if (t < s) red[t] += red[t+s]; __syncthreads(); }
    float norm2 = red[0];
    if (t == 0) invnorms[n] = 1.0f / norm2;
    __syncthreads();

    // cbF (GEMM1 B frag order): frag(ks,nt): lane l, elem j = cb[nt*16+(l&15)][ks*32+(l>>4)*8+j]
    {
        int ks = t >> 5, g = (t >> 3) & 3, j = t & 7;
        cbF[((size_t)(ks*16 + (n >> 4))*64 + g*16 + (n & 15))*8 + j] = f2bf(cbn[ks*32 + g*8 + j]);
    }
    // cbTF (GEMM2 A frag order): frag(ks,ct): lane l, elem j = cbT[ct*16+(l&15)][ks*32+(l>>4)*8+j]
    {
        int ct = t >> 4, cl = t & 15;
        int ks = n >> 5, g = (n >> 3) & 3, j = n & 7;
        cbTF[((size_t)(ks*16 + ct)*64 + g*16 + cl)*8 + j] = f2bf(cbn[ct*16 + cl]);
    }
    // cosim: thread m handles codebook_pub row m (vectorized)
    float dot = 0.f, np2 = 0.f;
    const float4* pm4 = (const float4*)(cbp + (size_t)t*256);
    for (int c4 = 0; c4 < 64; ++c4) {
        float4 pv = pm4[c4];
        dot += cbn[c4*4+0]*pv.x + cbn[c4*4+1]*pv.y + cbn[c4*4+2]*pv.z + cbn[c4*4+3]*pv.w;
        np2 += pv.x*pv.x + pv.y*pv.y + pv.z*pv.z + pv.w*pv.w;
    }
    float cosv = dot * rsqrtf(norm2 * np2);
    __syncthreads();
    red[t] = cosv;
    __syncthreads();
    for (int s = 128; s > 0; s >>= 1) { if (t < s) red[t] = fmaxf(red[t], red[t+s]); __syncthreads(); }
    if (t == 0) {
        int maskedv = (red[0] <= 0.5f) ? 1 : 0;
        if (maskedv) atomicOr((u32*)&meta[1 + (n >> 5)], 1u << (n & 31));
        else         atomicAdd(&meta[0], 1);
    }
}

// ---------------- K1: fused transpose + GEMM1 + sigmoid -> w_all [img][p][n]
// 64-px tile, 4 waves; wave wv owns codes [wv*64, +64). A in frag-order LDS,
// B in registers, halved (16 frags live) for occupancy.
__global__ __launch_bounds__(256, 3) void k_gemm1f(const float* __restrict__ feat,
                                                   const u16* __restrict__ cbF,
                                                   const float* __restrict__ invnorms,
                                                   u16* __restrict__ w_all,
                                                   const int* __restrict__ meta) {
    __shared__ alignas(16) u16 alds[32*64*8];   // 32 frags (m*8+ks) x 64 lanes x 8 = 32 KB
    int bid = blockIdx.x;
    int img = bid / PTILES, pt = bid % PTILES;
    if ((img & 1) && (meta[0] == 0)) return;    // all-masked: odd images' own w unused
    int p0 = pt * PT;
    int t = threadIdx.x, wv = t >> 6, l = t & 63;
    int lr = l & 15, lg = l >> 4;

    short8 breg[16];
    #pragma unroll
    for (int nt2 = 0; nt2 < 2; ++nt2)
        #pragma unroll
        for (int ks = 0; ks < 8; ++ks)
            breg[nt2*8 + ks] = *(const short8*)(cbF + ((size_t)((ks*16 + wv*4 + nt2)*64 + l))*8);

    // ---- stage A: feature[c][p] f32 -> bf16 fragment-order LDS ----
    int px = t & 63;
    int cgrp = t >> 6;
    const float* fb = feat + ((size_t)img*CC)*PP + p0 + px;
    int m_ = px >> 4;
    int lslot = px & 15;
    #pragma unroll
    for (int i = 0; i < 16; ++i) {
        int c0 = i*16 + cgrp*4;
        float f0 = fb[(size_t)(c0+0)*PP];
        float f1 = fb[(size_t)(c0+1)*PP];
        float f2 = fb[(size_t)(c0+2)*PP];
        float f3 = fb[(size_t)(c0+3)*PP];
        u32 lo = (u32)f2bf(f0) | ((u32)f2bf(f1) << 16);
        u32 hi = (u32)f2bf(f2) | ((u32)f2bf(f3) << 16);
        int ks = c0 >> 5;
        int lane = lslot + (((c0 >> 3) & 3) << 4);
        u32* dst = (u32*)((char*)alds + ((size_t)((m_*8 + ks)*64 + lane))*16 + (c0 & 7)*2);
        dst[0] = lo; dst[1] = hi;
    }
    __syncthreads();

    #pragma unroll
    for (int nh = 0; nh < 2; ++nh) {
        if (nh) {
            #pragma unroll
            for (int nt2 = 0; nt2 < 2; ++nt2)
                #pragma unroll
                for (int ks = 0; ks < 8; ++ks)
                    breg[nt2*8 + ks] = *(const short8*)(cbF + ((size_t)((ks*16 + wv*4 + 2 + nt2)*64 + l))*8);
        }
        float invn[2];
        #pragma unroll
        for (int nt2 = 0; nt2 < 2; ++nt2) invn[nt2] = invnorms[wv*64 + (nh*2 + nt2)*16 + lr];
        #pragma unroll
        for (int m = 0; m < 4; ++m) {
            f32x4 acc[2];
            acc[0] = (f32x4){0.f,0.f,0.f,0.f};
            acc[1] = (f32x4){0.f,0.f,0.f,0.f};
            #pragma unroll
            for (int ks = 0; ks < 8; ++ks) {
                short8 a = *(const short8*)(alds + ((size_t)((m*8 + ks)*64 + l))*8);
                acc[0] = __builtin_amdgcn_mfma_f32_16x16x32_bf16(a, breg[ks],     acc[0], 0, 0, 0);
                acc[1] = __builtin_amdgcn_mfma_f32_16x16x32_bf16(a, breg[8 + ks], acc[1], 0, 0, 0);
            }
            #pragma unroll
            for (int nt2 = 0; nt2 < 2; ++nt2) {
                #pragma unroll
                for (int r = 0; r < 4; ++r) {
                    int p = p0 + m*16 + lg*4 + r;
                    int n = wv*64 + (nh*2 + nt2)*16 + lr;
                    float x = acc[nt2][r] * invn[nt2];
                    float w = 1.f / (1.f + __expf(-x));
                    w_all[((size_t)img*PP + p)*256 + n] = f2bf(w);
                }
            }
        }
    }
}

// ---------------- K2: select/warp + softmax + GEMM2 -> out ----------------
// smx LDS row-major [64 p][256 n] bf16 with XOR swizzle byte^=((p&7)<<4):
// conflict-free for both softmax b128 writes and B-frag b128 reads.
__device__ inline u32 smx_off(int p, int n) {
    return (u32)(((p*256 + n)*2) ^ ((p & 7) << 4));
}

__global__ __launch_bounds__(256, 3) void k_out(const u16* __restrict__ w_all,
                                                const u16* __restrict__ cbTF,
                                                const int* __restrict__ meta,
                                                const float* __restrict__ am,
                                                float* __restrict__ out) {
    __shared__ alignas(16) u16 smx[64*256];   // 32 KB
    int bid = blockIdx.x;
    int img = bid / PTILES, pt = bid % PTILES;
    int p0 = pt * PT;
    int t = threadIdx.x;
    bool allm = (meta[0] == 0);

    // ---- phase A: build softmax'd weights tile in LDS ----
    {
        int pl = t >> 2, q = t & 3;            // pixel-local, n-quarter
        int p = p0 + pl;
        u32 mb0 = (u32)meta[1 + q*2], mb1 = (u32)meta[2 + q*2];
        bool ego_only = (img & 1) && allm;
        float vals[64];
        if (!ego_only) {
            const u16* own = w_all + ((size_t)img*PP + p)*256 + q*64;
            #pragma unroll
            for (int i = 0; i < 8; ++i) {
                short8 v = *(const short8*)(own + i*8);
                #pragma unroll
                for (int j = 0; j < 8; ++j) vals[i*8 + j] = bf2f((u16)v[j]);
            }
        } else {
            #pragma unroll
            for (int i = 0; i < 64; ++i) vals[i] = 0.f;
        }
        if (img & 1) {   // masked codes get warped agent-0 weights
            int hh = p / WW, ww = p % WW;
            const float* th = am + (size_t)img*12;    // affine_matrix[bb][j][0]
            float gx = ww * (2.f/(WW-1)) - 1.f;
            float gy = hh * (2.f/(HH-1)) - 1.f;
            float xr = th[0]*gx + th[1]*gy + th[2];
            float yr = th[3]*gx + th[4]*gy + th[5];
            float x = (xr + 1.f) * ((WW-1)*0.5f);
            float y = (yr + 1.f) * ((HH-1)*0.5f);
            float x0f = floorf(x), y0f = floorf(y);
            float dx = x - x0f, dy = y - y0f;
            int x0 = (int)x0f, y0 = (int)y0f;
            float wc4[4] = {(1.f-dx)*(1.f-dy), dx*(1.f-dy), (1.f-dx)*dy, dx*dy};
            int xs_[4] = {x0, x0+1, x0, x0+1};
            int ys_[4] = {y0, y0, y0+1, y0+1};
            const u16* w0 = w_all + ((size_t)(img-1)*PP)*256;
            const u16* cptr[4];
            #pragma unroll
            for (int k = 0; k < 4; ++k) {
                bool ok = (xs_[k] >= 0) & (xs_[k] < WW) & (ys_[k] >= 0) & (ys_[k] < HH);
                cptr[k] = ok ? (w0 + ((size_t)(ys_[k]*WW + xs_[k]))*256 + q*64) : nullptr;
            }
            #pragma unroll
            for (int ch = 0; ch < 4; ++ch) {
                float wch[16];
                #pragma unroll
                for (int i = 0; i < 16; ++i) wch[i] = 0.f;
                #pragma unroll
                for (int k = 0; k < 4; ++k) {
                    if (cptr[k]) {
                        const u16* cp = cptr[k] + ch*16;
                        short8 a = *(const short8*)(cp);
                        short8 b = *(const short8*)(cp + 8);
                        float wk = wc4[k];
                        #pragma unroll
                        for (int j = 0; j < 8; ++j) { wch[j] += wk*bf2f((u16)a[j]); wch[8+j] += wk*bf2f((u16)b[j]); }
                    }
                }
                u32 mb = (ch < 2) ? mb0 : mb1;
                #pragma unroll
                for (int i = 0; i < 16; ++i) {
                    int bit = (ch & 1)*16 + i;
                    if ((mb >> bit) & 1) vals[ch*16 + i] = wch[i];
                }
            }
        }
        // softmax over 256 codes = 4 lanes x 64 values
        float m = vals[0];
        #pragma unroll
        for (int i = 1; i < 64; ++i) m = fmaxf(m, vals[i]);
        m = fmaxf(m, __shfl_xor(m, 1));
        m = fmaxf(m, __shfl_xor(m, 2));
        float s = 0.f;
        #pragma unroll
        for (int i = 0; i < 64; ++i) { vals[i] = __expf(vals[i] - m); s += vals[i]; }
        s += __shfl_xor(s, 1);
        s += __shfl_xor(s, 2);
        float inv = 1.f / s;
        #pragma unroll
        for (int i = 0; i < 8; ++i) {
            short8 v;
            #pragma unroll
            for (int j = 0; j < 8; ++j) v[j] = (short)f2bf(vals[i*8 + j] * inv);
            *(short8*)((char*)smx + smx_off(pl, q*64 + i*8)) = v;
        }
    }
    __syncthreads();

    // ---- phase B: GEMM2  out[c][p] = sum_n cbT[c][n] * smx[p][n] ----
    int wv = t >> 6, l = t & 63;
    int lr = l & 15, lg = l >> 4;
    #pragma unroll
    for (int ch = 0; ch < 2; ++ch) {
        short8 areg[16];
        #pragma unroll
        for (int ct2 = 0; ct2 < 2; ++ct2)
            #pragma unroll
            for (int ks = 0; ks < 8; ++ks)
                areg[ct2*8 + ks] = *(const short8*)(cbTF + ((size_t)((ks*16 + wv*4 + ch*2 + ct2)*64 + l))*8);
        f32x4 acc[2][4];
        #pragma unroll
        for (int i = 0; i < 2; ++i)
            #pragma unroll
            for (int j = 0; j < 4; ++j) acc[i][j] = (f32x4){0.f,0.f,0.f,0.f};
        #pragma unroll
        for (int ks = 0; ks < 8; ++ks) {
            short8 b[4];
            #pragma unroll
            for (int p4 = 0; p4 < 4; ++p4)
                b[p4] = *(const short8*)((char*)smx + smx_off(p4*16 + lr, ks*32 + lg*8));
            #pragma unroll
            for (int ct2 = 0; ct2 < 2; ++ct2)
                #pragma unroll
                for (int p4 = 0; p4 < 4; ++p4)
                    acc[ct2][p4] = __builtin_amdgcn_mfma_f32_16x16x32_bf16(areg[ct2*8 + ks], b[p4], acc[ct2][p4], 0, 0, 0);
        }
        #pragma unroll
        for (int ct2 = 0; ct2 < 2; ++ct2)
            #pragma unroll
            for (int p4 = 0; p4 < 4; ++p4)
                #pragma unroll
                for (int r = 0; r < 4; ++r) {
                    int c = wv*64 + (ch*2 + ct2)*16 + lg*4 + r;
                    int p = p0 + p4*16 + lr;
                    out[((size_t)img*CC + c)*PP + p] = acc[ct2][p4][r];
                }
    }
}

extern "C" void kernel_launch(void* const* d_in, const int* in_sizes, int n_in,
                              void* d_out, int out_size, void* d_ws, size_t ws_size,
                              hipStream_t stream) {
    const float* feature = (const float*)d_in[0];
    const float* cb      = (const float*)d_in[1];
    const float* cbp     = (const float*)d_in[2];
    const float* am      = (const float*)d_in[3];
    float* out = (float*)d_out;

    char* ws = (char*)d_ws;
    size_t o = 0;
    u16* w_all = (u16*)(ws + o); o += (size_t)NIMG*PP*NCODE*2; // 75.5 MB
    u16* cbF   = (u16*)(ws + o); o += 256*256*2;
    u16* cbTF  = (u16*)(ws + o); o += 256*256*2;
    float* invnorms = (float*)(ws + o); o += 256*4;
    int* meta       = (int*)(ws + o);   o += 9*4;

    hipMemsetAsync(meta, 0, 9*4, stream);
    hipLaunchKernelGGL(k_prep, dim3(256), dim3(256), 0, stream, cb, cbp, invnorms, meta, cbF, cbTF);
    hipLaunchKernelGGL(k_gemm1f, dim3(NIMG*PTILES), dim3(256), 0, stream, feature, cbF, invnorms, w_all, meta);
    hipLaunchKernelGGL(k_out, dim3(NIMG*PTILES), dim3(256), 0, stream, w_all, cbTF, meta, am, out);
}